// Round 1
// baseline (1049.949 us; speedup 1.0000x reference)
//
#include <hip/hip_runtime.h>
#include <stdint.h>
#include <math.h>

typedef short bf16x8 __attribute__((ext_vector_type(8)));
typedef float f32x4 __attribute__((ext_vector_type(4)));

#if __has_builtin(__builtin_amdgcn_exp2f)
#define EXP2F(x) __builtin_amdgcn_exp2f(x)
#else
#define EXP2F(x) exp2f(x)
#endif

static constexpr int Bn   = 2;
static constexpr int Sn   = 2048;
static constexpr int NH   = 32;
static constexpr int NKV  = 8;
static constexpr int Dh   = 128;
static constexpr int En   = NH * Dh;     // 4096
static constexpr int KVEn = NKV * Dh;    // 1024
static constexpr int MT   = Bn * Sn;     // 4096 tokens

__device__ __forceinline__ unsigned short f2bf(float f) {
  unsigned int u = __float_as_uint(f);
  u += 0x7FFFu + ((u >> 16) & 1u);
  return (unsigned short)(u >> 16);
}
__device__ __forceinline__ float bf2f(unsigned short h) {
  return __uint_as_float(((unsigned int)h) << 16);
}

typedef __attribute__((address_space(1))) void* gas_t;
typedef __attribute__((address_space(3))) void* las_t;
// async global->LDS, 16B per lane; lds dest must be wave-base + lane*16 (linear)
__device__ __forceinline__ void gl_lds16(const void* g, void* l) {
  __builtin_amdgcn_global_load_lds((gas_t)(uintptr_t)g, (las_t)(uint32_t)(uintptr_t)l,
                                   16, 0, 0);
}

// ---------------- pre/post passes ----------------

__global__ void cast_bf16_kernel(const float* __restrict__ x,
                                 unsigned short* __restrict__ y, int n4) {
  int i = blockIdx.x * 256 + threadIdx.x;
  if (i >= n4) return;
  float4 v = ((const float4*)x)[i];
  ushort4 o;
  o.x = f2bf(v.x); o.y = f2bf(v.y); o.z = f2bf(v.z); o.w = f2bf(v.w);
  ((ushort4*)y)[i] = o;
}

// W [R][C] f32 -> WT [C][R] bf16 (tiled, coalesced both sides)
__global__ void tcast_kernel(const float* __restrict__ W,
                             unsigned short* __restrict__ WT, int R, int C) {
  __shared__ float t[32][33];
  int tx = threadIdx.x, ty = threadIdx.y;
  int c = blockIdx.x * 32 + tx, r = blockIdx.y * 32 + ty;
  t[ty][tx] = W[(size_t)r * C + c];
  __syncthreads();
  int ro = blockIdx.x * 32 + ty, co = blockIdx.y * 32 + tx;
  WT[(size_t)ro * R + co] = f2bf(t[tx][ty]);
}

__global__ void rope_table_kernel(float2* __restrict__ cs) {
  int i = blockIdx.x * 256 + threadIdx.x;   // i < Sn*64
  int s = i >> 6, d = i & 63;
  float inv = powf(10000.0f, -(float)d * (1.0f / 64.0f));
  float a = (float)s * inv;
  cs[i] = make_float2(cosf(a), sinf(a));
}

// in-place RoPE on [MT][heads*128]; pairs (d, d+64); optional scale folded in
__global__ void rope_kernel(unsigned short* __restrict__ q,
                            const float2* __restrict__ cs, int heads, float scl) {
  int row = blockIdx.x;
  int s = row & (Sn - 1);
  int hl = threadIdx.x >> 6, d = threadIdx.x & 63;
  int h = blockIdx.y * 4 + hl;
  size_t base = (size_t)row * (heads * Dh) + (size_t)h * Dh + d;
  float2 c = cs[s * 64 + d];
  float x0 = bf2f(q[base]), x1 = bf2f(q[base + 64]);
  q[base]      = f2bf((x0 * c.x - x1 * c.y) * scl);
  q[base + 64] = f2bf((x1 * c.x + x0 * c.y) * scl);
}

// Vl [MT][KVEn] -> Vt [B][KV][D][S]  (d-major so PV B-frags are k-contiguous)
__global__ void vtrans_kernel(const unsigned short* __restrict__ Vl,
                              unsigned short* __restrict__ Vt) {
  __shared__ unsigned short t[32][33];
  int bk = blockIdx.z;                 // b*NKV+kv
  int b = bk >> 3, kv = bk & 7;
  int d = blockIdx.x * 32 + threadIdx.x;
  int s = blockIdx.y * 32 + threadIdx.y;
  t[threadIdx.y][threadIdx.x] = Vl[((size_t)(b * Sn + s)) * KVEn + kv * Dh + d];
  __syncthreads();
  int dd = blockIdx.x * 32 + threadIdx.y;
  int so = blockIdx.y * 32 + threadIdx.x;
  Vt[((size_t)bk * Dh + dd) * Sn + so] = t[threadIdx.x][threadIdx.y];
}

// ---------------- GEMM (m97 structure): A[M,K] bf16, BT[N,K] bf16 -> C[M,N] ----------------

__global__ __launch_bounds__(256) void gemm_kernel(
    const unsigned short* __restrict__ A, const unsigned short* __restrict__ BT,
    void* __restrict__ Cout, int M, int N, int K, int out_f32) {
  __shared__ unsigned short As[128 * 32];
  __shared__ unsigned short Bs[128 * 32];
  const int tid = threadIdx.x;
  const int lane = tid & 63, wave = tid >> 6;
  const int r15 = lane & 15, kg = lane >> 4;
  const int m0 = blockIdx.y * 128, n0 = blockIdx.x * 128;
  const int wr = (wave >> 1) * 64, wc = (wave & 1) * 64;
  const char* Ab = (const char*)A;
  const char* Bb = (const char*)BT;

  f32x4 acc[4][4] = {};

  for (int k0 = 0; k0 < K; k0 += 32) {
    {
      int f0 = tid * 16;            // [0,4096)
      int f1 = f0 + 4096;           // [4096,8192)
      int r0 = f0 >> 6, o0 = f0 & 63;
      int r1 = f1 >> 6, o1 = f1 & 63;
      gl_lds16(Ab + ((size_t)(m0 + r0) * K + k0) * 2 + o0, (char*)As + f0);
      gl_lds16(Ab + ((size_t)(m0 + r1) * K + k0) * 2 + o1, (char*)As + f1);
      gl_lds16(Bb + ((size_t)(n0 + r0) * K + k0) * 2 + o0, (char*)Bs + f0);
      gl_lds16(Bb + ((size_t)(n0 + r1) * K + k0) * 2 + o1, (char*)Bs + f1);
    }
    __syncthreads();
    bf16x8 a[4], b[4];
#pragma unroll
    for (int i = 0; i < 4; ++i)
      a[i] = *(const bf16x8*)&As[(wr + i * 16 + r15) * 32 + kg * 8];
#pragma unroll
    for (int i = 0; i < 4; ++i)
      b[i] = *(const bf16x8*)&Bs[(wc + i * 16 + r15) * 32 + kg * 8];
#pragma unroll
    for (int i = 0; i < 4; ++i)
#pragma unroll
      for (int j = 0; j < 4; ++j)
        acc[i][j] = __builtin_amdgcn_mfma_f32_16x16x32_bf16(a[i], b[j], acc[i][j], 0, 0, 0);
    __syncthreads();
  }

#pragma unroll
  for (int i = 0; i < 4; ++i)
#pragma unroll
    for (int j = 0; j < 4; ++j)
#pragma unroll
      for (int t = 0; t < 4; ++t) {
        int row = m0 + wr + i * 16 + kg * 4 + t;   // C/D: row=(l>>4)*4+reg
        int col = n0 + wc + j * 16 + r15;          //      col=l&15
        if (out_f32)
          ((float*)Cout)[(size_t)row * N + col] = acc[i][j][t];
        else
          ((unsigned short*)Cout)[(size_t)row * N + col] = f2bf(acc[i][j][t]);
      }
}

// ---------------- flash attention (causal, GQA) ----------------
// grid (S/64, NH, B), 256 thr. Q pre-scaled by (1/sqrt(D))*log2(e); K raw.
__global__ __launch_bounds__(256) void attn_kernel(
    const unsigned short* __restrict__ Q, const unsigned short* __restrict__ Kl,
    const unsigned short* __restrict__ Vt, unsigned short* __restrict__ AO) {
  __shared__ unsigned short Ks[64 * 128];    // [kv][d], rows XOR-swizzled
  __shared__ unsigned short Vs[128 * 64];    // [d][kv], rows XOR-swizzled
  __shared__ unsigned short Ps[4][16 * 64];  // per-wave P, swizzled
  const int tid = threadIdx.x, lane = tid & 63, wave = tid >> 6;
  const int qt = blockIdx.x, h = blockIdx.y, b = blockIdx.z;
  const int kvh = h >> 2;                    // G = 4
  const int r15 = lane & 15, kg = lane >> 4;
  const int qrow0 = qt * 64 + wave * 16;

  bf16x8 qf[4];
#pragma unroll
  for (int db = 0; db < 4; ++db)
    qf[db] = *(const bf16x8*)&Q[((size_t)(b * Sn + qrow0 + r15)) * En + h * Dh + db * 32 + kg * 8];

  f32x4 o[8] = {};
  float mrow[4] = {-1e30f, -1e30f, -1e30f, -1e30f};
  float lrow[4] = {0.f, 0.f, 0.f, 0.f};

  const char* Kbase = (const char*)Kl + ((size_t)b * Sn) * (KVEn * 2) + kvh * 256;
  const char* Vbase = (const char*)Vt + ((size_t)(b * NKV + kvh) * Dh) * (Sn * 2);

  for (int kt = 0; kt <= qt; ++kt) {
    // stage K tile 64x128 (swizzle on the global source; LDS dest linear)
#pragma unroll
    for (int c = 0; c < 4; ++c) {
      int f = (c * 256 + tid) * 16;
      int row = f >> 8, cb = f & 255;
      gl_lds16(Kbase + (size_t)(kt * 64 + row) * (KVEn * 2) + (cb ^ ((row & 7) << 4)),
               (char*)Ks + f);
    }
    // stage V^T tile 128x64
#pragma unroll
    for (int c = 0; c < 4; ++c) {
      int f = (c * 256 + tid) * 16;
      int row = f >> 7, cb = f & 127;
      gl_lds16(Vbase + (size_t)row * (Sn * 2) + kt * 128 + (cb ^ ((row & 7) << 4)),
               (char*)Vs + f);
    }
    __syncthreads();

    // QK^T
    f32x4 sc[4] = {};
#pragma unroll
    for (int db = 0; db < 4; ++db) {
#pragma unroll
      for (int kf = 0; kf < 4; ++kf) {
        int krow = kf * 16 + r15;
        int cb = (db * 32 + kg * 8) * 2;
        bf16x8 kb = *(const bf16x8*)((const char*)Ks + krow * 256 + (cb ^ ((krow & 7) << 4)));
        sc[kf] = __builtin_amdgcn_mfma_f32_16x16x32_bf16(qf[db], kb, sc[kf], 0, 0, 0);
      }
    }
    if (kt == qt) {   // causal mask inside diagonal tile
#pragma unroll
      for (int kf = 0; kf < 4; ++kf) {
        int kvg = kf * 16 + r15;
#pragma unroll
        for (int t = 0; t < 4; ++t) {
          int qg = wave * 16 + kg * 4 + t;
          if (kvg > qg) sc[kf][t] = -1e30f;
        }
      }
    }
    // online softmax (row lives across the 16 lanes of a quarter-wave)
    float mx[4], sm[4];
#pragma unroll
    for (int t = 0; t < 4; ++t) {
      float v = fmaxf(fmaxf(sc[0][t], sc[1][t]), fmaxf(sc[2][t], sc[3][t]));
#pragma unroll
      for (int off = 1; off < 16; off <<= 1) v = fmaxf(v, __shfl_xor(v, off, 16));
      mx[t] = fmaxf(mrow[t], v);
      sm[t] = EXP2F(mrow[t] - mx[t]);
      mrow[t] = mx[t];
    }
#pragma unroll
    for (int kf = 0; kf < 4; ++kf)
#pragma unroll
      for (int t = 0; t < 4; ++t)
        sc[kf][t] = EXP2F(sc[kf][t] - mx[t]);
    float ps[4];
#pragma unroll
    for (int t = 0; t < 4; ++t) {
      float v = sc[0][t] + sc[1][t] + sc[2][t] + sc[3][t];
#pragma unroll
      for (int off = 1; off < 16; off <<= 1) v += __shfl_xor(v, off, 16);
      ps[t] = v;
      lrow[t] = lrow[t] * sm[t] + ps[t];
    }
#pragma unroll
    for (int nf = 0; nf < 8; ++nf)
#pragma unroll
      for (int t = 0; t < 4; ++t) o[nf][t] *= sm[t];

    // P (C-layout) -> per-wave LDS (A-layout source), swizzled
    char* Pw = (char*)Ps[wave];
#pragma unroll
    for (int kf = 0; kf < 4; ++kf)
#pragma unroll
      for (int t = 0; t < 4; ++t) {
        int r = kg * 4 + t, c = kf * 16 + r15;
        *(unsigned short*)(Pw + r * 128 + ((c * 2) ^ ((r & 7) << 4))) = f2bf(sc[kf][t]);
      }
    // PV
#pragma unroll
    for (int ks = 0; ks < 2; ++ks) {
      bf16x8 pa = *(const bf16x8*)(Pw + r15 * 128 + ((kg * 16 + ks * 64) ^ ((r15 & 7) << 4)));
#pragma unroll
      for (int nf = 0; nf < 8; ++nf) {
        int vrow = nf * 16 + r15;
        int cb = (ks * 32 + kg * 8) * 2;
        bf16x8 vb = *(const bf16x8*)((const char*)Vs + vrow * 128 + (cb ^ ((vrow & 7) << 4)));
        o[nf] = __builtin_amdgcn_mfma_f32_16x16x32_bf16(pa, vb, o[nf], 0, 0, 0);
      }
    }
    __syncthreads();
  }

  float rinv[4];
#pragma unroll
  for (int t = 0; t < 4; ++t) rinv[t] = 1.0f / lrow[t];
#pragma unroll
  for (int nf = 0; nf < 8; ++nf)
#pragma unroll
    for (int t = 0; t < 4; ++t) {
      int srow = qt * 64 + wave * 16 + kg * 4 + t;
      AO[((size_t)(b * Sn + srow)) * En + h * Dh + nf * 16 + r15] = f2bf(o[nf][t] * rinv[t]);
    }
}

// ---------------- launch ----------------

extern "C" void kernel_launch(void* const* d_in, const int* in_sizes, int n_in,
                              void* d_out, int out_size, void* d_ws, size_t ws_size,
                              hipStream_t stream) {
  const float* x  = (const float*)d_in[0];
  const float* Wq = (const float*)d_in[1];
  const float* Wk = (const float*)d_in[2];
  const float* Wv = (const float*)d_in[3];
  const float* Wo = (const float*)d_in[4];

  char* ws = (char*)d_ws;
  size_t off = 0;
  auto alloc = [&](size_t bytes) -> char* {
    char* p = ws + off;
    off += (bytes + 255) & ~(size_t)255;
    return p;
  };
  unsigned short* xb  = (unsigned short*)alloc((size_t)MT * En * 2);
  unsigned short* WqT = (unsigned short*)alloc((size_t)En * En * 2);
  unsigned short* WkT = (unsigned short*)alloc((size_t)KVEn * En * 2);
  unsigned short* WvT = (unsigned short*)alloc((size_t)KVEn * En * 2);
  unsigned short* WoT = (unsigned short*)alloc((size_t)En * En * 2);
  unsigned short* Ql  = (unsigned short*)alloc((size_t)MT * En * 2);
  unsigned short* Kl  = (unsigned short*)alloc((size_t)MT * KVEn * 2);
  unsigned short* Vl  = (unsigned short*)alloc((size_t)MT * KVEn * 2);
  unsigned short* Vt  = (unsigned short*)alloc((size_t)MT * KVEn * 2);
  float2* cs          = (float2*)alloc((size_t)Sn * 64 * sizeof(float2));
  unsigned short* AO  = xb;   // alias: xb dead after the V projection

  cast_bf16_kernel<<<MT * (En / 4) / 256, 256, 0, stream>>>(x, xb, MT * En / 4);
  tcast_kernel<<<dim3(En / 32, En / 32), dim3(32, 32), 0, stream>>>(Wq, WqT, En, En);
  tcast_kernel<<<dim3(KVEn / 32, En / 32), dim3(32, 32), 0, stream>>>(Wk, WkT, En, KVEn);
  tcast_kernel<<<dim3(KVEn / 32, En / 32), dim3(32, 32), 0, stream>>>(Wv, WvT, En, KVEn);
  tcast_kernel<<<dim3(En / 32, En / 32), dim3(32, 32), 0, stream>>>(Wo, WoT, En, En);
  rope_table_kernel<<<Sn * 64 / 256, 256, 0, stream>>>(cs);

  gemm_kernel<<<dim3(En / 128, MT / 128), 256, 0, stream>>>(xb, WqT, Ql, MT, En, En, 0);
  gemm_kernel<<<dim3(KVEn / 128, MT / 128), 256, 0, stream>>>(xb, WkT, Kl, MT, KVEn, En, 0);
  gemm_kernel<<<dim3(KVEn / 128, MT / 128), 256, 0, stream>>>(xb, WvT, Vl, MT, KVEn, En, 0);

  const float scl = 0.08838834764831845f * 1.4426950408889634f; // (1/sqrt(128))*log2(e)
  rope_kernel<<<dim3(MT, NH / 4), 256, 0, stream>>>(Ql, cs, NH, scl);
  rope_kernel<<<dim3(MT, NKV / 4), 256, 0, stream>>>(Kl, cs, NKV, 1.0f);
  vtrans_kernel<<<dim3(Dh / 32, Sn / 32, Bn * NKV), dim3(32, 32), 0, stream>>>(Vl, Vt);

  attn_kernel<<<dim3(Sn / 64, NH, Bn), 256, 0, stream>>>(Ql, Kl, Vt, AO);

  gemm_kernel<<<dim3(En / 128, MT / 128), 256, 0, stream>>>(AO, WoT, d_out, MT, En, En, 1);
}